// Round 11
// baseline (311.698 us; speedup 1.0000x reference)
//
#include <hip/hip_runtime.h>

typedef _Float16 f16x8 __attribute__((ext_vector_type(8)));
typedef _Float16 f16x4 __attribute__((ext_vector_type(4)));
typedef float    f32x4 __attribute__((ext_vector_type(4)));

static __device__ __forceinline__ f32x4 mfma16(f16x8 a, f16x8 b, f32x4 c) {
    return __builtin_amdgcn_mfma_f32_16x16x32_f16(a, b, c, 0, 0, 0);
}

// async global->LDS, 16B per lane; LDS dest is wave-uniform base + lane*16
static __device__ __forceinline__ void gload_lds16(const _Float16* g, _Float16* lds) {
    __builtin_amdgcn_global_load_lds(
        (const __attribute__((address_space(1))) unsigned int*)g,
        (__attribute__((address_space(3))) unsigned int*)lds, 16, 0, 0);
}

// ---------------------------------------------------------------------------
// Kernel 1: fused Bayesian weight sampling (+KL partials) and dec_inp cvt.
// blocks [0,1024): sample+KL, float4-vectorized (4 elems/thread x 12 streams).
// blocks [1024,3072): fp32->fp16 convert of dec_inp, 4x float4 per thread.
// ---------------------------------------------------------------------------
__global__ __launch_bounds__(256) void k_prep(
    const float* __restrict__ qm, const float* __restrict__ km, const float* __restrict__ vm,
    const float* __restrict__ qs, const float* __restrict__ ks, const float* __restrict__ vs,
    const float* __restrict__ om, const float* __restrict__ os,
    const float* __restrict__ eq, const float* __restrict__ ek,
    const float* __restrict__ ev, const float* __restrict__ eo,
    _Float16* __restrict__ wq, _Float16* __restrict__ wk,
    _Float16* __restrict__ wv, _Float16* __restrict__ wo,
    float* __restrict__ part,
    const float* __restrict__ dec, _Float16* __restrict__ xh)
{
    if (blockIdx.x >= 1024) {
        int base = (blockIdx.x - 1024) * 4096;
        #pragma unroll
        for (int rp = 0; rp < 4; ++rp) {
            int i = base + rp * 1024 + threadIdx.x * 4;
            float4 v = *(const float4*)&dec[i];
            f16x4 hv;
            hv[0] = (_Float16)v.x; hv[1] = (_Float16)v.y;
            hv[2] = (_Float16)v.z; hv[3] = (_Float16)v.w;
            *(f16x4*)&xh[i] = hv;
        }
        return;
    }
    int i = (blockIdx.x * 256 + threadIdx.x) * 4;
    f32x4 aqm = *(const f32x4*)&qm[i], akm = *(const f32x4*)&km[i], avm = *(const f32x4*)&vm[i];
    f32x4 aqs = *(const f32x4*)&qs[i], aks = *(const f32x4*)&ks[i], avs = *(const f32x4*)&vs[i];
    f32x4 aom = *(const f32x4*)&om[i], aos = *(const f32x4*)&os[i];
    f32x4 veq = *(const f32x4*)&eq[i], vek = *(const f32x4*)&ek[i];
    f32x4 vev = *(const f32x4*)&ev[i], veo = *(const f32x4*)&eo[i];
    f16x4 hq, hk, hv, ho;
    float t = 0.f;
    #pragma unroll
    for (int j = 0; j < 4; ++j) {
        hq[j] = (_Float16)(aqm[j] + veq[j] * __expf(aqs[j]));
        hk[j] = (_Float16)(akm[j] + vek[j] * __expf(aks[j]));
        hv[j] = (_Float16)(avm[j] + vev[j] * __expf(avs[j]));
        // faithful bug: output weight from value_mean + eps_o*exp(output_std)
        ho[j] = (_Float16)(avm[j] + veo[j] * __expf(aos[j]));
        t += aqm[j]*aqm[j] - 2.f*aqs[j] + __expf(2.f*aqs[j])
           + akm[j]*akm[j] - 2.f*aks[j] + __expf(2.f*aks[j])
           + avm[j]*avm[j] - 2.f*avs[j] + __expf(2.f*avs[j])
           + aom[j]*aom[j] - 2.f*aos[j] + __expf(2.f*aos[j]);
    }
    *(f16x4*)&wq[i] = hq;
    *(f16x4*)&wk[i] = hk;
    *(f16x4*)&wv[i] = hv;
    *(f16x4*)&wo[i] = ho;
    #pragma unroll
    for (int m = 1; m < 64; m <<= 1) t += __shfl_xor(t, m, 64);
    __shared__ float red[4];
    int w = threadIdx.x >> 6, lane = threadIdx.x & 63;
    if (lane == 0) red[w] = t;
    __syncthreads();
    if (threadIdx.x == 0) part[blockIdx.x] = red[0] + red[1] + red[2] + red[3];
}

// ---------------------------------------------------------------------------
// Kernel 2/3/5: C = A(M,K) * B(N,K)^T, 128x128 tile, BK=64, m97 structure.
// (Proven 678TF structure. CLOCK CANARY: byte-stable code+counters across
// rounds — 74.6us/z-slice-triple @ r5 clock, ~77 @ r10, 92 @ r9 slow box.)
// LDS k-chunks XOR-swizzled (chunk c of row r lives at pos c^(r&7)).
//
// mode 0 (Q/K): standard. Block remap xcd = flat&7 owns M-tile group.
//   z==0 slice (Q) pre-scaled by 0.125*log2e (softmax runs in exp2 domain).
// mode 1 (proj): xout = resid + C (fp32).
// mode 2 (V-transposed, replaces k_vtrans): compute Vt[b*1024 + wcol][s]
//   directly — per-b GEMM with A = Wv (M=1024 weight rows), B = X_b
//   (token rows s, B-row stride 8K + b*K; per-lane gload_lds src makes the
//   strided slice free). Same tile/loop/FLOPs; epilogue writes
//   (b*1024 + i)*1024 + j. Kills vtrans' 32MB HBM round-trip (~6.5us).
//   XCD remap: xcd = b -> each XCD reads Wv(2MB)+X_b(2MB) = its 4MB L2.
// ---------------------------------------------------------------------------
__global__ __launch_bounds__(256) void k_gemm(
    const _Float16* __restrict__ A, const _Float16* __restrict__ B0,
    _Float16* __restrict__ C0, const float* __restrict__ resid,
    float* __restrict__ xout, int mode)
{
    __shared__ __align__(16) _Float16 As[128 * 64];
    __shared__ __align__(16) _Float16 Bs[128 * 64];
    const int K = 1024, N = 1024;
    const _Float16* Bp = B0 + (size_t)blockIdx.z * 1048576u;
    _Float16* Cp = C0 + (size_t)blockIdx.z * 8388608u;
    int flat = blockIdx.y * 8 + blockIdx.x;        // 0..511
    int tM, tN, b2 = 0;
    if (mode == 2) {
        b2 = flat & 7;                             // XCD = batch slice
        int j = flat >> 3;                         // 0..63
        tM = (j & 7) * 128;                        // Wv row tile
        tN = (j >> 3) * 128;                       // s tile
    } else {
        int xcd = flat & 7, j = flat >> 3;
        tM = (xcd * 8 + (j & 7)) * 128;            // M-group per XCD
        tN = (j >> 3) * 128;
    }
    int tid = threadIdx.x, w = tid >> 6, lane = tid & 63;
    int wm = w & 1, wn = w >> 1;
    int q = lane >> 4, r = lane & 15;
    int csrc = ((lane & 7) ^ (lane >> 3)) * 8;
    int srow = lane >> 3;
    // B-row address: mode 2 reads the per-b token slice X_b[s][k] =
    // XH[(s*8+b)*K + k]  ->  row stride 8K, base offset b*K.
    const size_t bstride = (mode == 2) ? (size_t)(8 * K) : (size_t)K;
    const _Float16* Bbase = Bp + (size_t)b2 * K;
    f32x4 acc[4][4] = {};
    for (int kk = 0; kk < K; kk += 64) {
        __syncthreads();            // prior ds_reads drained before restaging
        #pragma unroll
        for (int i = 0; i < 4; ++i) {
            int chunk = w * 4 + i;                 // 16 x 1KB chunks per matrix
            int row = chunk * 8 + srow;            // 0..127
            gload_lds16(A     + (size_t)(tM + row) * K + kk + csrc, &As[chunk * 512]);
            gload_lds16(Bbase + (size_t)(tN + row) * bstride + kk + csrc, &Bs[chunk * 512]);
        }
        __syncthreads();            // vmcnt(0) drain lands the LDS data
        #pragma unroll
        for (int kc = 0; kc < 2; ++kc) {
            f16x8 af[4], bf[4];
            #pragma unroll
            for (int m = 0; m < 4; ++m) {
                int row = wm*64 + m*16 + r;
                int pos = ((kc*4 + q) ^ (r & 7)) * 8;
                af[m] = *(const f16x8*)&As[row*64 + pos];
            }
            #pragma unroll
            for (int n = 0; n < 4; ++n) {
                int row = wn*64 + n*16 + r;
                int pos = ((kc*4 + q) ^ (r & 7)) * 8;
                bf[n] = *(const f16x8*)&Bs[row*64 + pos];
            }
            #pragma unroll
            for (int m = 0; m < 4; ++m)
                #pragma unroll
                for (int n = 0; n < 4; ++n)
                    acc[m][n] = mfma16(af[m], bf[n], acc[m][n]);
        }
    }
    // Q scale: 1/sqrt(64) * log2(e) -> scores arrive in log2 domain
    float sc = (mode == 0 && blockIdx.z == 0) ? 0.1803368801f : 1.0f;
    // epilogue: C/D layout row = q*4+t, col = r  (verified m89/m91)
    #pragma unroll
    for (int m = 0; m < 4; ++m)
      #pragma unroll
      for (int n = 0; n < 4; ++n)
        #pragma unroll
        for (int t = 0; t < 4; ++t) {
            int row = tM + wm*64 + m*16 + q*4 + t;
            int col = tN + wn*64 + n*16 + r;
            if (mode == 2) {
                // Vt[(b*1024 + Wv-row)][s]
                Cp[(size_t)(b2 * 1024 + row) * 1024 + col] = (_Float16)acc[m][n][t];
            } else {
                size_t o = (size_t)row * N + col;
                if (mode == 0) Cp[o] = (_Float16)(acc[m][n][t] * sc);
                else           xout[o] = resid[o] + acc[m][n][t];
            }
        }
}

// ---------------------------------------------------------------------------
// Kernel 4: causal flash attention, S^T formulation, K/V double-buffered.
//   S^T = K·Q^T  -> lane holds j in registers (16/lane), i = lane r
//   softmax over j (exp2 domain; scores pre-scaled by log2e in k_gemm):
//   in-register tree + 2 shuffles (xor 16/32)
//   O^T = V^T·P^T via mfma(A=V^T frag, B=P frag); P via vectorized LDS
// P buffer: chunk-XOR swizzle, stride 64 — writes cover all 32 banks
// uniformly (r10), reads unchanged-optimal. Ps 16KB (LDS 48KB, 3 blk/CU).
// T14 async-stage: tile t+1 staged at top of tile t body (proven r2).
// T5: setprio(1) around both MFMA clusters (proven r4).
// T13: defer-max, THR = 8*log2e = 11.54 in log2 domain (proven r4).
// Balanced causal dispatch via qt remap f=[0,4,7,3,2,6,5,1].
// ---------------------------------------------------------------------------
__global__ __launch_bounds__(256, 3) void k_attn(
    const _Float16* __restrict__ Qb, const _Float16* __restrict__ Kb,
    const _Float16* __restrict__ Vtg, _Float16* __restrict__ AVo)
{
    __shared__ __align__(16) _Float16 Ks[2][64 * 64];  // rows j, cols d (swizzled)
    __shared__ __align__(16) _Float16 Vs[2][64 * 64];  // rows d, cols j (swizzled)
    __shared__ __align__(16) _Float16 Ps[4 * 32 * 64]; // per-wave P[i][j], swizzled
    const int bh = blockIdx.x;            // 0..127
    const int b = bh & 7, h = bh >> 3;
    const int cbh = b * 16 + h;           // Vt row-group index
    const int qt = (0x15623740u >> (blockIdx.y * 4)) & 7;  // balanced remap
    const int tid = threadIdx.x, w = tid >> 6, lane = tid & 63;
    const int q = lane >> 4, r = lane & 15;
    const int i0 = qt * 128 + w * 32;     // this wave's i-base
    const int csrc = ((lane & 7) ^ (lane >> 3)) * 8;
    const int srow = lane >> 3;

    f16x8 qf[2][2];                       // Q B-fragments (pre-scaled, log2 domain)
    #pragma unroll
    for (int it = 0; it < 2; ++it)
      #pragma unroll
      for (int kc = 0; kc < 2; ++kc)
        qf[it][kc] = *(const f16x8*)&Qb[((size_t)(i0 + it*16 + r)*8 + b)*1024 + h*64 + kc*32 + q*8];

    f32x4 ot[4][2] = {};                  // O^T acc: [dtb][it], d=dtb*16+q*4+t, i=it*16+r
    float mrun[2] = {-1e30f, -1e30f}, lrun[2] = {0.f, 0.f};
    _Float16* Pw = &Ps[w * 2048];
    const int pwr = ((q & 1) * 4);        // sub-chunk offset for P writes

    auto stage = [&](int kt, int buf) __attribute__((always_inline)) {
        #pragma unroll
        for (int ii = 0; ii < 2; ++ii) {  // K-tile + Vt-tile, 8KB each
            int chunk = w * 2 + ii;
            int row = chunk * 8 + srow;
            gload_lds16(Kb  + ((size_t)(kt*64 + row)*8 + b)*1024 + h*64 + csrc, &Ks[buf][chunk*512]);
            gload_lds16(Vtg + ((size_t)(cbh*64 + row))*1024 + kt*64 + csrc,     &Vs[buf][chunk*512]);
        }
    };

    auto tile = [&](int kt, int buf, bool MASK) __attribute__((always_inline)) {
        f32x4 st[4][2] = {};              // S^T: [jt][it], j=jt*16+q*4+t, i=it*16+r
        #pragma unroll
        for (int kc = 0; kc < 2; ++kc) {
            f16x8 kf[4];
            #pragma unroll
            for (int jt = 0; jt < 4; ++jt) {
                int pos = ((kc*4 + q) ^ (r & 7)) * 8;
                kf[jt] = *(const f16x8*)&Ks[buf][(jt*16 + r)*64 + pos];
            }
            __builtin_amdgcn_s_setprio(1);
            #pragma unroll
            for (int jt = 0; jt < 4; ++jt)
              #pragma unroll
              for (int it = 0; it < 2; ++it)
                st[jt][it] = mfma16(kf[jt], qf[it][kc], st[jt][it]);
            __builtin_amdgcn_s_setprio(0);
        }

        #pragma unroll
        for (int it = 0; it < 2; ++it) {
            if (MASK) {
                int il = i0 + it*16 + r;
                #pragma unroll
                for (int jt = 0; jt < 4; ++jt)
                  #pragma unroll
                  for (int t = 0; t < 4; ++t)
                    if (kt*64 + jt*16 + q*4 + t > il) st[jt][it][t] = -1e30f;
            }
            float mx = -1e30f;            // in-register max over 16 j values
            #pragma unroll
            for (int jt = 0; jt < 4; ++jt) {
                f32x4 s4 = st[jt][it];
                mx = fmaxf(mx, fmaxf(fmaxf(s4[0], s4[1]), fmaxf(s4[2], s4[3])));
            }
            mx = fmaxf(mx, __shfl_xor(mx, 16, 64));
            mx = fmaxf(mx, __shfl_xor(mx, 32, 64));
            // T13 defer-max (log2 domain): rescale only when max grew by >8*log2e
            if (!__all(mx - mrun[it] <= 11.5416f)) {
                float mnew = fmaxf(mrun[it], mx);
                float al = exp2f(mrun[it] - mnew);
                lrun[it] *= al;
                #pragma unroll
                for (int dtb = 0; dtb < 4; ++dtb) ot[dtb][it] *= al;
                mrun[it] = mnew;
            }
            float mref = mrun[it];
            float ps = 0.f;
            #pragma unroll
            for (int jt = 0; jt < 4; ++jt) {   // exp2 + pack + swizzled LDS write
                f16x4 hv;
                #pragma unroll
                for (int t = 0; t < 4; ++t) {
                    float e = exp2f(st[jt][it][t] - mref);
                    ps += e;
                    hv[t] = (_Float16)e;
                }
                int pos = ((jt*2 + (q >> 1)) ^ (r & 7)) * 8 + pwr;
                *(f16x4*)&Pw[(it*16 + r)*64 + pos] = hv;
            }
            ps += __shfl_xor(ps, 16, 64);
            ps += __shfl_xor(ps, 32, 64);
            lrun[it] += ps;
        }

        #pragma unroll
        for (int kc = 0; kc < 2; ++kc) {  // O^T += V^T-frag x P-frag
            f16x8 vf[4], pf[2];
            #pragma unroll
            for (int dtb = 0; dtb < 4; ++dtb) {
                int pos = ((kc*4 + q) ^ (r & 7)) * 8;
                vf[dtb] = *(const f16x8*)&Vs[buf][(dtb*16 + r)*64 + pos];
            }
            #pragma unroll
            for (int it = 0; it < 2; ++it) {
                int pos = ((kc*4 + q) ^ (r & 7)) * 8;
                pf[it] = *(const f16x8*)&Pw[(it*16 + r)*64 + pos];
            }
            __builtin_amdgcn_s_setprio(1);
            #pragma unroll
            for (int dtb = 0; dtb < 4; ++dtb)
              #pragma unroll
              for (int it = 0; it < 2; ++it)
                ot[dtb][it] = mfma16(vf[dtb], pf[it], ot[dtb][it]);
            __builtin_amdgcn_s_setprio(0);
        }
    };

    // prologue: stage tile 0; __syncthreads drains vmcnt -> tile 0 ready
    stage(0, 0);
    __syncthreads();
    for (int kt = 0; kt < 2*qt; ++kt) {                 // interior: no mask
        stage(kt + 1, (kt + 1) & 1);
        tile(kt, kt & 1, false);
        __syncthreads();
    }
    {   // diagonal tiles (always exist)
        int kt = 2*qt;
        stage(kt + 1, (kt + 1) & 1);
        tile(kt, kt & 1, true);
        __syncthreads();
        tile(kt + 1, (kt + 1) & 1, true);
    }

    #pragma unroll
    for (int it = 0; it < 2; ++it) {
        float inv = 1.f / lrun[it];
        int s = i0 + it*16 + r;
        #pragma unroll
        for (int dtb = 0; dtb < 4; ++dtb) {
            f16x4 hv;
            #pragma unroll
            for (int t = 0; t < 4; ++t) hv[t] = (_Float16)(ot[dtb][it][t] * inv);
            *(f16x4*)&AVo[((size_t)s*8 + b)*1024 + h*64 + dtb*16 + q*4] = hv;
        }
    }
}

// ---------------------------------------------------------------------------
// Kernel 6: in-place LayerNorm, wave-per-row, 4 rows/block (no LDS, no
// __syncthreads — wave-wide shfl reduce only). block 2048 = KL finalize.
// ---------------------------------------------------------------------------
__global__ __launch_bounds__(256) void k_ln(float* __restrict__ x,
    const float* __restrict__ g, const float* __restrict__ bta,
    const float* __restrict__ part)
{
    int w = threadIdx.x >> 6, lane = threadIdx.x & 63;
    if (blockIdx.x == 2048) {             // KL finalize (1024 partials)
        __shared__ float rs[4];
        float s = 0.f;
        for (int i = threadIdx.x; i < 1024; i += 256) s += part[i];
        #pragma unroll
        for (int m = 1; m < 64; m <<= 1) s += __shfl_xor(s, m, 64);
        if (lane == 0) rs[w] = s;
        __syncthreads();
        if (threadIdx.x == 0)
            x[8388608] = (rs[0] + rs[1] + rs[2] + rs[3]) * (0.5f / 4194304.f);
        return;
    }
    int row = blockIdx.x * 4 + w;         // one wave per row
    float* xr = x + (size_t)row * 1024;
    float4 v[4];
    float s = 0.f, s2 = 0.f;
    #pragma unroll
    for (int rp = 0; rp < 4; ++rp) {
        v[rp] = *(const float4*)&xr[rp * 256 + lane * 4];
        s  += v[rp].x + v[rp].y + v[rp].z + v[rp].w;
        s2 += v[rp].x*v[rp].x + v[rp].y*v[rp].y + v[rp].z*v[rp].z + v[rp].w*v[rp].w;
    }
    #pragma unroll
    for (int m = 1; m < 64; m <<= 1) { s += __shfl_xor(s, m, 64); s2 += __shfl_xor(s2, m, 64); }
    float mu = s * (1.f / 1024.f);
    float var = s2 * (1.f / 1024.f) - mu * mu;
    float rstd = rsqrtf(var + 1e-5f);
    #pragma unroll
    for (int rp = 0; rp < 4; ++rp) {
        float4 gv = *(const float4*)&g[rp * 256 + lane * 4];
        float4 bv = *(const float4*)&bta[rp * 256 + lane * 4];
        float4 ov;
        ov.x = (v[rp].x - mu) * rstd * gv.x + bv.x;
        ov.y = (v[rp].y - mu) * rstd * gv.y + bv.y;
        ov.z = (v[rp].z - mu) * rstd * gv.z + bv.z;
        ov.w = (v[rp].w - mu) * rstd * gv.w + bv.w;
        *(float4*)&xr[rp * 256 + lane * 4] = ov;
    }
}

// ---------------------------------------------------------------------------
extern "C" void kernel_launch(void* const* d_in, const int* in_sizes, int n_in,
                              void* d_out, int out_size, void* d_ws, size_t ws_size,
                              hipStream_t stream)
{
    (void)in_sizes; (void)n_in; (void)out_size; (void)ws_size;
    const float* dec   = (const float*)d_in[0];
    // d_in[1] = attn_mask: statically causal (j > i), not read
    const float* qm    = (const float*)d_in[2];
    const float* km    = (const float*)d_in[3];
    const float* vm    = (const float*)d_in[4];
    const float* qs    = (const float*)d_in[5];
    const float* ks    = (const float*)d_in[6];
    const float* vs    = (const float*)d_in[7];
    const float* om    = (const float*)d_in[8];
    const float* os    = (const float*)d_in[9];
    const float* gamma = (const float*)d_in[10];
    const float* beta  = (const float*)d_in[11];
    const float* eq    = (const float*)d_in[12];
    const float* ek    = (const float*)d_in[13];
    const float* ev    = (const float*)d_in[14];
    const float* eo    = (const float*)d_in[15];

    char* ws = (char*)d_ws;
    _Float16* WQ   = (_Float16*)ws;                       // 4 x 1M fp16 = 8 MB
    float*    PART = (float*)(ws + (8ull  << 20));        // 4 KB
    _Float16* XH   = (_Float16*)(ws + (9ull  << 20));     // 16 MB
    _Float16* Qh   = (_Float16*)(ws + (25ull << 20));     // Q,K,Vt contiguous 48 MB
    _Float16* Kh   = Qh + 8388608;
    _Float16* Vt   = Qh + 16777216;                       // Vt written by mode-2 GEMM
    _Float16* AV   = XH;                                  // XH dead after both GEMMs
    float*    out  = (float*)d_out;                       // x fp32 lives in d_out

    k_prep<<<dim3(3072), dim3(256), 0, stream>>>(
        qm, km, vm, qs, ks, vs, om, os, eq, ek, ev, eo,
        WQ, WQ + 1048576, WQ + 2097152, WQ + 3145728, PART, dec, XH);
    // Q (z=0, scaled) + K (z=1)
    k_gemm<<<dim3(8, 64, 2), dim3(256), 0, stream>>>(XH, WQ, Qh, dec, out, 0);
    // V directly transposed into Vt (replaces the old V GEMM + k_vtrans)
    k_gemm<<<dim3(8, 64, 1), dim3(256), 0, stream>>>(WQ + 2097152, XH, Vt, dec, out, 2);
    k_attn<<<dim3(128, 8), dim3(256), 0, stream>>>(Qh, Kh, Vt, AV);
    k_gemm<<<dim3(8, 64, 1), dim3(256), 0, stream>>>(AV, WQ + 3145728, Qh, dec, out, 1);
    k_ln<<<dim3(2049), dim3(256), 0, stream>>>(out, gamma, beta, PART);
}